// Round 1
// baseline (969.769 us; speedup 1.0000x reference)
//
#include <hip/hip_runtime.h>

#define N_NODES  100000
#define N_EDGES  1600000
#define IN_CH    64
#define HID      128
#define N_GRAPHS 512
#define LN_EPS   1e-5f

#define SCAN_CHUNK  1024
#define SCAN_BLOCKS ((N_NODES + SCAN_CHUNK - 1) / SCAN_CHUNK)  // 98

// ---------------- CSR build ----------------

__global__ void count_edges(const int* __restrict__ dst, int* __restrict__ cnt) {
    int e = blockIdx.x * blockDim.x + threadIdx.x;
    if (e < N_EDGES) atomicAdd(&cnt[dst[e]], 1);
}

__global__ void scan_block_sums(const int* __restrict__ cnt, int* __restrict__ bsum) {
    __shared__ int sh[256];
    int base = blockIdx.x * SCAN_CHUNK;
    int t = threadIdx.x;
    int s = 0;
    for (int j = t; j < SCAN_CHUNK; j += 256) {
        int i = base + j;
        s += (i < N_NODES) ? cnt[i] : 0;
    }
    sh[t] = s; __syncthreads();
    for (int off = 128; off > 0; off >>= 1) {
        if (t < off) sh[t] += sh[t + off];
        __syncthreads();
    }
    if (t == 0) bsum[blockIdx.x] = sh[0];
}

__global__ void scan_bsum_exclusive(int* __restrict__ bsum, int* __restrict__ offsets) {
    // single block, 128 threads, scans SCAN_BLOCKS (=98) values
    __shared__ int sh[128];
    int t = threadIdx.x;
    int v = (t < SCAN_BLOCKS) ? bsum[t] : 0;
    sh[t] = v; __syncthreads();
    for (int off = 1; off < 128; off <<= 1) {
        int add = (t >= off) ? sh[t - off] : 0;
        __syncthreads();
        sh[t] += add;
        __syncthreads();
    }
    if (t < SCAN_BLOCKS) bsum[t] = sh[t] - v;   // exclusive
    if (t == 127) offsets[N_NODES] = sh[127];   // grand total (= N_EDGES)
}

__global__ void scan_write_offsets(const int* __restrict__ cnt, const int* __restrict__ bsum,
                                   int* __restrict__ offsets) {
    __shared__ int sh[256];
    int b = blockIdx.x, t = threadIdx.x;
    int base = b * SCAN_CHUNK + t * 4;
    int c[4];
    #pragma unroll
    for (int j = 0; j < 4; j++) {
        int i = base + j;
        c[j] = (i < N_NODES) ? cnt[i] : 0;
    }
    int tsum = c[0] + c[1] + c[2] + c[3];
    sh[t] = tsum; __syncthreads();
    for (int off = 1; off < 256; off <<= 1) {
        int add = (t >= off) ? sh[t - off] : 0;
        __syncthreads();
        sh[t] += add;
        __syncthreads();
    }
    int run = sh[t] - tsum + bsum[b];  // exclusive prefix + block base
    #pragma unroll
    for (int j = 0; j < 4; j++) {
        int i = base + j;
        if (i < N_NODES) offsets[i] = run;
        run += c[j];
    }
}

__global__ void fill_csr(const int* __restrict__ src, const int* __restrict__ dst,
                         const int* __restrict__ offsets, int* __restrict__ cursor,
                         int* __restrict__ csr) {
    int e = blockIdx.x * blockDim.x + threadIdx.x;
    if (e < N_EDGES) {
        int d = dst[e];
        int pos = offsets[d] + atomicAdd(&cursor[d], 1);
        csr[pos] = src[e];
    }
}

// ---------------- mean aggregation (gather via CSR) ----------------

template<int F>
__global__ __launch_bounds__(256)
void aggregate(const float* __restrict__ in, const int* __restrict__ offsets,
               const int* __restrict__ csr, float* __restrict__ out) {
    int wave = threadIdx.x >> 6;
    int lane = threadIdx.x & 63;
    int n = blockIdx.x * 4 + wave;
    if (n >= N_NODES) return;
    int o0 = offsets[n], o1 = offsets[n + 1];
    float inv = 1.0f / (float)((o1 - o0) > 1 ? (o1 - o0) : 1);
    if (F == 64) {
        float acc = 0.f;
        for (int o = o0; o < o1; o++) {
            int s = csr[o];
            acc += in[s * 64 + lane];
        }
        out[n * 64 + lane] = acc * inv;
    } else {
        const float2* in2 = (const float2*)in;
        float ax = 0.f, ay = 0.f;
        for (int o = o0; o < o1; o++) {
            int s = csr[o];
            float2 v = in2[s * 64 + lane];
            ax += v.x; ay += v.y;
        }
        ((float2*)out)[n * 64 + lane] = make_float2(ax * inv, ay * inv);
    }
}

// ---------------- fused dual GEMM: out = relu(A1@W1 + A2@W2 + bias) ----------------
// A1: [M][K1], W1: [K1][128], A2: [M][K2], W2: [K2][128]

#define BM 64
#define BN 128
#define BK 32

__global__ __launch_bounds__(256)
void gemm_fused(const float* __restrict__ A1, int K1, const float* __restrict__ W1,
                const float* __restrict__ A2, int K2, const float* __restrict__ W2,
                const float* __restrict__ bias, float* __restrict__ out) {
    __shared__ float As[BM][BK + 1];
    __shared__ float Bs[BK][BN + 4];
    int t  = threadIdx.x;
    int tx = t & 15, ty = t >> 4;
    int rowBase = blockIdx.x * BM;

    float acc[4][8];
    #pragma unroll
    for (int i = 0; i < 4; i++)
        #pragma unroll
        for (int j = 0; j < 8; j++) acc[i][j] = 0.f;

    const float* Aptr[2] = {A1, A2};
    const float* Wptr[2] = {W1, W2};
    int Ks[2] = {K1, K2};

    for (int ph = 0; ph < 2; ph++) {
        const float* A = Aptr[ph];
        const float* W = Wptr[ph];
        int K = Ks[ph];
        for (int k0 = 0; k0 < K; k0 += BK) {
            // A tile: 64 rows x 32 cols = 512 float4, 2 per thread
            #pragma unroll
            for (int i = 0; i < 2; i++) {
                int q = t + i * 256;
                int r = q >> 3;
                int cf = q & 7;
                int gr = rowBase + r;
                float4 v = (gr < N_NODES) ? ((const float4*)(A + (size_t)gr * K + k0))[cf]
                                          : make_float4(0.f, 0.f, 0.f, 0.f);
                As[r][cf * 4 + 0] = v.x; As[r][cf * 4 + 1] = v.y;
                As[r][cf * 4 + 2] = v.z; As[r][cf * 4 + 3] = v.w;
            }
            // W tile: 32 rows x 128 cols = 1024 float4, 4 per thread
            #pragma unroll
            for (int i = 0; i < 4; i++) {
                int q = t + i * 256;
                int r = q >> 5;
                int cf = q & 31;
                float4 v = ((const float4*)(W + (size_t)(k0 + r) * BN))[cf];
                *((float4*)&Bs[r][cf * 4]) = v;
            }
            __syncthreads();
            #pragma unroll
            for (int kk = 0; kk < BK; kk++) {
                float a[4];
                #pragma unroll
                for (int i = 0; i < 4; i++) a[i] = As[ty * 4 + i][kk];
                float4 b0 = *((float4*)&Bs[kk][tx * 8]);
                float4 b1 = *((float4*)&Bs[kk][tx * 8 + 4]);
                float b[8] = {b0.x, b0.y, b0.z, b0.w, b1.x, b1.y, b1.z, b1.w};
                #pragma unroll
                for (int i = 0; i < 4; i++)
                    #pragma unroll
                    for (int j = 0; j < 8; j++)
                        acc[i][j] += a[i] * b[j];
            }
            __syncthreads();
        }
    }

    #pragma unroll
    for (int i = 0; i < 4; i++) {
        int gr = rowBase + ty * 4 + i;
        if (gr < N_NODES) {
            float o[8];
            #pragma unroll
            for (int j = 0; j < 8; j++)
                o[j] = fmaxf(acc[i][j] + bias[tx * 8 + j], 0.f);
            float4* dst4 = (float4*)(out + (size_t)gr * BN + tx * 8);
            dst4[0] = make_float4(o[0], o[1], o[2], o[3]);
            dst4[1] = make_float4(o[4], o[5], o[6], o[7]);
        }
    }
}

// ---------------- pool + LayerNorm + decode ----------------

__global__ __launch_bounds__(128)
void pool_ln_decode(const float* __restrict__ h, const int* __restrict__ batch,
                    const float* __restrict__ ln_g, const float* __restrict__ ln_b,
                    const float* __restrict__ Wd, const float* __restrict__ bd,
                    float* __restrict__ out) {
    __shared__ float red[128];
    __shared__ int bounds[2];
    int g = blockIdx.x, c = threadIdx.x;
    if (c < 2) {
        int target = g + c;
        int lo = 0, hi = N_NODES;
        while (lo < hi) {
            int mid = (lo + hi) >> 1;
            if (batch[mid] < target) lo = mid + 1; else hi = mid;
        }
        bounds[c] = lo;
    }
    __syncthreads();
    int start = bounds[0], end = bounds[1];

    float s = 0.f;
    for (int r = start; r < end; r++) s += h[(size_t)r * 128 + c];

    // mean
    red[c] = s; __syncthreads();
    for (int off = 64; off > 0; off >>= 1) {
        if (c < off) red[c] += red[c + off];
        __syncthreads();
    }
    float mu = red[0] * (1.0f / 128.f);
    __syncthreads();

    float d = s - mu;
    red[c] = d * d; __syncthreads();
    for (int off = 64; off > 0; off >>= 1) {
        if (c < off) red[c] += red[c + off];
        __syncthreads();
    }
    float var = red[0] * (1.0f / 128.f);
    __syncthreads();

    float gn = d * rsqrtf(var + LN_EPS) * ln_g[c] + ln_b[c];

    red[c] = gn * Wd[c * 2 + 0]; __syncthreads();
    for (int off = 64; off > 0; off >>= 1) {
        if (c < off) red[c] += red[c + off];
        __syncthreads();
    }
    float o0 = red[0];
    __syncthreads();

    red[c] = gn * Wd[c * 2 + 1]; __syncthreads();
    for (int off = 64; off > 0; off >>= 1) {
        if (c < off) red[c] += red[c + off];
        __syncthreads();
    }
    if (c == 0) {
        out[g * 2 + 0] = o0 + bd[0];
        out[g * 2 + 1] = red[0] + bd[1];
    }
}

// ---------------- host launcher ----------------

extern "C" void kernel_launch(void* const* d_in, const int* in_sizes, int n_in,
                              void* d_out, int out_size, void* d_ws, size_t ws_size,
                              hipStream_t stream) {
    (void)in_sizes; (void)n_in; (void)out_size; (void)ws_size;

    const float* x     = (const float*)d_in[0];
    const int*   ei    = (const int*)d_in[1];
    const int*   batch = (const int*)d_in[2];
    const float* Wl0 = (const float*)d_in[3];
    const float* bl0 = (const float*)d_in[4];
    const float* Wr0 = (const float*)d_in[5];
    const float* Wl1 = (const float*)d_in[6];
    const float* bl1 = (const float*)d_in[7];
    const float* Wr1 = (const float*)d_in[8];
    const float* Wl2 = (const float*)d_in[9];
    const float* bl2 = (const float*)d_in[10];
    const float* Wr2 = (const float*)d_in[11];
    const float* ln_g = (const float*)d_in[12];
    const float* ln_b = (const float*)d_in[13];
    const float* Wd  = (const float*)d_in[14];
    const float* bd  = (const float*)d_in[15];
    float* out = (float*)d_out;

    const int* src = ei;
    const int* dst = ei + N_EDGES;

    // workspace layout (bytes)
    char* ws = (char*)d_ws;
    int*   csr     = (int*)(ws + 0);            //  6,400,000
    int*   offsets = (int*)(ws + 6400000);      //    400,004 (N+1 ints)
    int*   cnt     = (int*)(ws + 6800128);      //    400,000
    int*   cursor  = (int*)(ws + 7200128);      //    400,000
    int*   bsum    = (int*)(ws + 7600128);      //        512
    float* bufA    = (float*)(ws + 7600640);    // 51,200,000
    float* bufB    = (float*)(ws + 58800640);   // 51,200,000
    float* bufC    = (float*)(ws + 110000640);  // 51,200,000
    // total: 161,200,640 bytes

    hipMemsetAsync(cnt, 0, N_NODES * sizeof(int), stream);
    hipMemsetAsync(cursor, 0, N_NODES * sizeof(int), stream);

    count_edges<<<(N_EDGES + 255) / 256, 256, 0, stream>>>(dst, cnt);
    scan_block_sums<<<SCAN_BLOCKS, 256, 0, stream>>>(cnt, bsum);
    scan_bsum_exclusive<<<1, 128, 0, stream>>>(bsum, offsets);
    scan_write_offsets<<<SCAN_BLOCKS, 256, 0, stream>>>(cnt, bsum, offsets);
    fill_csr<<<(N_EDGES + 255) / 256, 256, 0, stream>>>(src, dst, offsets, cursor, csr);

    const int aggGrid = N_NODES / 4;        // 25000 (exact)
    const int gemmGrid = (N_NODES + BM - 1) / BM;  // 1563

    // layer 0: agg(x)[64] -> A ; h1 = relu(A@Wl0 + x@Wr0 + bl0) -> B
    aggregate<64><<<aggGrid, 256, 0, stream>>>(x, offsets, csr, bufA);
    gemm_fused<<<gemmGrid, 256, 0, stream>>>(bufA, 64, Wl0, x, 64, Wr0, bl0, bufB);
    // layer 1: agg(h1)[128] -> A ; h2 = relu(A@Wl1 + h1@Wr1 + bl1) -> C
    aggregate<128><<<aggGrid, 256, 0, stream>>>(bufB, offsets, csr, bufA);
    gemm_fused<<<gemmGrid, 256, 0, stream>>>(bufA, 128, Wl1, bufB, 128, Wr1, bl1, bufC);
    // layer 2: agg(h2)[128] -> A ; h3 = relu(A@Wl2 + h2@Wr2 + bl2) -> B
    aggregate<128><<<aggGrid, 256, 0, stream>>>(bufC, offsets, csr, bufA);
    gemm_fused<<<gemmGrid, 256, 0, stream>>>(bufA, 128, Wl2, bufC, 128, Wr2, bl2, bufB);

    pool_ln_decode<<<N_GRAPHS, 128, 0, stream>>>(bufB, batch, ln_g, ln_b, Wd, bd, out);
}

// Round 2
// 830.888 us; speedup vs baseline: 1.1671x; 1.1671x over previous
//
#include <hip/hip_runtime.h>

#define N_NODES  100000
#define N_EDGES  1600000
#define N_GRAPHS 512
#define LN_EPS   1e-5f

#define SCAN_CHUNK  1024
#define SCAN_BLOCKS ((N_NODES + SCAN_CHUNK - 1) / SCAN_CHUNK)  // 98

typedef unsigned short u16;
typedef unsigned int   u32;
typedef __attribute__((ext_vector_type(8))) short bf16x8;
typedef __attribute__((ext_vector_type(4))) float f32x4;

__device__ __forceinline__ float b2f(u16 v) {
    u32 u = ((u32)v) << 16;
    return __builtin_bit_cast(float, u);
}
__device__ __forceinline__ u16 f2b(float f) {
    u32 u = __builtin_bit_cast(u32, f);
    u32 r = (u + 0x7fffu + ((u >> 16) & 1u)) >> 16;  // RNE
    return (u16)r;
}

// ---------------- CSR build ----------------

__global__ void count_edges(const int* __restrict__ dst, int* __restrict__ cnt) {
    int e = blockIdx.x * blockDim.x + threadIdx.x;
    if (e < N_EDGES) atomicAdd(&cnt[dst[e]], 1);
}

__global__ void scan_block_sums(const int* __restrict__ cnt, int* __restrict__ bsum) {
    __shared__ int sh[256];
    int base = blockIdx.x * SCAN_CHUNK;
    int t = threadIdx.x;
    int s = 0;
    for (int j = t; j < SCAN_CHUNK; j += 256) {
        int i = base + j;
        s += (i < N_NODES) ? cnt[i] : 0;
    }
    sh[t] = s; __syncthreads();
    for (int off = 128; off > 0; off >>= 1) {
        if (t < off) sh[t] += sh[t + off];
        __syncthreads();
    }
    if (t == 0) bsum[blockIdx.x] = sh[0];
}

__global__ void scan_bsum_exclusive(int* __restrict__ bsum, int* __restrict__ offsets) {
    __shared__ int sh[128];
    int t = threadIdx.x;
    int v = (t < SCAN_BLOCKS) ? bsum[t] : 0;
    sh[t] = v; __syncthreads();
    for (int off = 1; off < 128; off <<= 1) {
        int add = (t >= off) ? sh[t - off] : 0;
        __syncthreads();
        sh[t] += add;
        __syncthreads();
    }
    if (t < SCAN_BLOCKS) bsum[t] = sh[t] - v;   // exclusive
    if (t == 127) offsets[N_NODES] = sh[127];
}

__global__ void scan_write_offsets(const int* __restrict__ cnt, const int* __restrict__ bsum,
                                   int* __restrict__ offsets) {
    __shared__ int sh[256];
    int b = blockIdx.x, t = threadIdx.x;
    int base = b * SCAN_CHUNK + t * 4;
    int c[4];
    #pragma unroll
    for (int j = 0; j < 4; j++) {
        int i = base + j;
        c[j] = (i < N_NODES) ? cnt[i] : 0;
    }
    int tsum = c[0] + c[1] + c[2] + c[3];
    sh[t] = tsum; __syncthreads();
    for (int off = 1; off < 256; off <<= 1) {
        int add = (t >= off) ? sh[t - off] : 0;
        __syncthreads();
        sh[t] += add;
        __syncthreads();
    }
    int run = sh[t] - tsum + bsum[b];
    #pragma unroll
    for (int j = 0; j < 4; j++) {
        int i = base + j;
        if (i < N_NODES) offsets[i] = run;
        run += c[j];
    }
}

__global__ void fill_csr(const int* __restrict__ src, const int* __restrict__ dst,
                         const int* __restrict__ offsets, int* __restrict__ cursor,
                         int* __restrict__ csr) {
    int e = blockIdx.x * blockDim.x + threadIdx.x;
    if (e < N_EDGES) {
        int d = dst[e];
        int pos = offsets[d] + atomicAdd(&cursor[d], 1);
        csr[pos] = src[e];
    }
}

// ---------------- dtype conversions ----------------

__global__ __launch_bounds__(256)
void conv_f32_bf16(const float* __restrict__ in, u16* __restrict__ out, int n4) {
    int i = blockIdx.x * 256 + threadIdx.x;
    if (i < n4) {
        float4 v = ((const float4*)in)[i];
        u32 lo = (u32)f2b(v.x) | ((u32)f2b(v.y) << 16);
        u32 hi = (u32)f2b(v.z) | ((u32)f2b(v.w) << 16);
        ((uint2*)out)[i] = make_uint2(lo, hi);
    }
}

// Wt[c][k] = bf16( k<K1 ? Wl[k][c] : Wr[k-K1][c] ), c in [0,128), k in [0,KC)
__global__ __launch_bounds__(256)
void conv_weights(const float* __restrict__ Wl, const float* __restrict__ Wr,
                  int K1, int KC, u16* __restrict__ Wt) {
    int idx = blockIdx.x * 256 + threadIdx.x;
    if (idx >= 128 * KC) return;
    int c = idx / KC, k = idx % KC;
    float v = (k < K1) ? Wl[k * 128 + c] : Wr[(k - K1) * 128 + c];
    Wt[idx] = f2b(v);
}

// ---------------- mean aggregation (bf16 gather via CSR) ----------------

template<int F>
__global__ __launch_bounds__(256)
void aggregate_bf16(const u16* __restrict__ in, const int* __restrict__ offsets,
                    const int* __restrict__ csr, u16* __restrict__ out) {
    int wv = threadIdx.x >> 6, lane = threadIdx.x & 63;
    int n = blockIdx.x * 4 + wv;
    if (n >= N_NODES) return;
    int o0 = offsets[n], o1 = offsets[n + 1];
    int d = o1 - o0;
    float inv = 1.0f / (float)(d > 1 ? d : 1);
    if (F == 128) {
        float ax = 0.f, ay = 0.f;
        for (int o = o0; o < o1; o++) {
            int s = csr[o];
            u32 v = ((const u32*)(in + (size_t)s * 128))[lane];
            ax += b2f((u16)(v & 0xffffu));
            ay += b2f((u16)(v >> 16));
        }
        u32 w = (u32)f2b(ax * inv) | ((u32)f2b(ay * inv) << 16);
        ((u32*)(out + (size_t)n * 128))[lane] = w;
    } else {
        float a = 0.f;
        for (int o = o0; o < o1; o++) {
            int s = csr[o];
            a += b2f(in[(size_t)s * 64 + lane]);
        }
        out[(size_t)n * 64 + lane] = f2b(a * inv);
    }
}

// ---------------- fused dual GEMM via MFMA ----------------
// out[M][128] = relu( A1[M][KHALF] @ W1 + A2[M][KHALF] @ W2 + bias ), bf16 in/out, fp32 acc.
// Wt[128][2*KHALF]: concatenated transposed weights (col-major-by-row: Wt[c][k]).
// Block: 256 threads = 4 waves, 64 rows. Wave w owns cols [w*32, w*32+32), all 64 rows.
// B fragments live in registers for the whole kernel (no LDS at all).

template<int KHALF>
__global__ __launch_bounds__(256)
void gemm_mfma(const u16* __restrict__ A1, const u16* __restrict__ A2,
               const u16* __restrict__ Wt, const float* __restrict__ bias,
               u16* __restrict__ out) {
    constexpr int KC  = 2 * KHALF;
    constexpr int NKS = KC / 32;

    int t = threadIdx.x;
    int lane = t & 63, w = t >> 6;
    int l15 = lane & 15, l4 = lane >> 4;
    int mbase = blockIdx.x * 64;

    // B fragments: 2 col-tiles x NKS k-steps, 8 bf16 each
    bf16x8 bfr[2][NKS];
    #pragma unroll
    for (int ct = 0; ct < 2; ct++)
        #pragma unroll
        for (int ks = 0; ks < NKS; ks++) {
            int row = w * 32 + ct * 16 + l15;          // output col
            int kb  = ks * 32 + l4 * 8;
            bfr[ct][ks] = *reinterpret_cast<const bf16x8*>(Wt + row * KC + kb);
        }

    f32x4 acc[4][2];
    #pragma unroll
    for (int i = 0; i < 4; i++)
        #pragma unroll
        for (int j = 0; j < 2; j++)
            acc[i][j] = (f32x4){0.f, 0.f, 0.f, 0.f};

    const bf16x8 zfr = {0, 0, 0, 0, 0, 0, 0, 0};

    #pragma unroll
    for (int ks = 0; ks < NKS; ks++) {
        const u16* Ab = (ks < NKS / 2) ? A1 : A2;
        int kb = (ks < NKS / 2) ? (ks * 32 + l4 * 8) : ((ks - NKS / 2) * 32 + l4 * 8);
        bf16x8 afr[4];
        #pragma unroll
        for (int rt = 0; rt < 4; rt++) {
            int row = mbase + rt * 16 + l15;
            afr[rt] = (row < N_NODES)
                ? *reinterpret_cast<const bf16x8*>(Ab + (size_t)row * KHALF + kb)
                : zfr;
        }
        #pragma unroll
        for (int rt = 0; rt < 4; rt++)
            #pragma unroll
            for (int ct = 0; ct < 2; ct++)
                acc[rt][ct] = __builtin_amdgcn_mfma_f32_16x16x32_bf16(
                    afr[rt], bfr[ct][ks], acc[rt][ct], 0, 0, 0);
    }

    // epilogue: bias + relu, store bf16. C/D: col=lane&15, row=(lane>>4)*4+reg
    #pragma unroll
    for (int ct = 0; ct < 2; ct++) {
        int col = w * 32 + ct * 16 + l15;
        float bv = bias[col];
        #pragma unroll
        for (int rt = 0; rt < 4; rt++) {
            #pragma unroll
            for (int j = 0; j < 4; j++) {
                int row = mbase + rt * 16 + l4 * 4 + j;
                if (row < N_NODES) {
                    float v = fmaxf(acc[rt][ct][j] + bv, 0.f);
                    out[(size_t)row * 128 + col] = f2b(v);
                }
            }
        }
    }
}

// ---------------- pool + LayerNorm + decode ----------------

__global__ __launch_bounds__(128)
void pool_ln_decode(const u16* __restrict__ h, const int* __restrict__ batch,
                    const float* __restrict__ ln_g, const float* __restrict__ ln_b,
                    const float* __restrict__ Wd, const float* __restrict__ bd,
                    float* __restrict__ out) {
    __shared__ float red[128];
    __shared__ int bounds[2];
    int g = blockIdx.x, c = threadIdx.x;
    if (c < 2) {
        int target = g + c;
        int lo = 0, hi = N_NODES;
        while (lo < hi) {
            int mid = (lo + hi) >> 1;
            if (batch[mid] < target) lo = mid + 1; else hi = mid;
        }
        bounds[c] = lo;
    }
    __syncthreads();
    int start = bounds[0], end = bounds[1];

    float s = 0.f;
    for (int r = start; r < end; r++) s += b2f(h[(size_t)r * 128 + c]);

    red[c] = s; __syncthreads();
    for (int off = 64; off > 0; off >>= 1) {
        if (c < off) red[c] += red[c + off];
        __syncthreads();
    }
    float mu = red[0] * (1.0f / 128.f);
    __syncthreads();

    float d = s - mu;
    red[c] = d * d; __syncthreads();
    for (int off = 64; off > 0; off >>= 1) {
        if (c < off) red[c] += red[c + off];
        __syncthreads();
    }
    float var = red[0] * (1.0f / 128.f);
    __syncthreads();

    float gn = d * rsqrtf(var + LN_EPS) * ln_g[c] + ln_b[c];

    red[c] = gn * Wd[c * 2 + 0]; __syncthreads();
    for (int off = 64; off > 0; off >>= 1) {
        if (c < off) red[c] += red[c + off];
        __syncthreads();
    }
    float o0 = red[0];
    __syncthreads();

    red[c] = gn * Wd[c * 2 + 1]; __syncthreads();
    for (int off = 64; off > 0; off >>= 1) {
        if (c < off) red[c] += red[c + off];
        __syncthreads();
    }
    if (c == 0) {
        out[g * 2 + 0] = o0 + bd[0];
        out[g * 2 + 1] = red[0] + bd[1];
    }
}

// ---------------- host launcher ----------------

extern "C" void kernel_launch(void* const* d_in, const int* in_sizes, int n_in,
                              void* d_out, int out_size, void* d_ws, size_t ws_size,
                              hipStream_t stream) {
    (void)in_sizes; (void)n_in; (void)out_size; (void)ws_size;

    const float* x     = (const float*)d_in[0];
    const int*   ei    = (const int*)d_in[1];
    const int*   batch = (const int*)d_in[2];
    const float* Wl0 = (const float*)d_in[3];
    const float* bl0 = (const float*)d_in[4];
    const float* Wr0 = (const float*)d_in[5];
    const float* Wl1 = (const float*)d_in[6];
    const float* bl1 = (const float*)d_in[7];
    const float* Wr1 = (const float*)d_in[8];
    const float* Wl2 = (const float*)d_in[9];
    const float* bl2 = (const float*)d_in[10];
    const float* Wr2 = (const float*)d_in[11];
    const float* ln_g = (const float*)d_in[12];
    const float* ln_b = (const float*)d_in[13];
    const float* Wd  = (const float*)d_in[14];
    const float* bd  = (const float*)d_in[15];
    float* out = (float*)d_out;

    const int* src = ei;
    const int* dst = ei + N_EDGES;

    // workspace layout (bytes)
    char* ws = (char*)d_ws;
    int* csr     = (int*)(ws + 0);            //  6,400,000
    int* offsets = (int*)(ws + 6400000);      //    400,004
    int* cnt     = (int*)(ws + 6800128);      //    400,000
    int* cursor  = (int*)(ws + 7200128);      //    400,000
    int* bsum    = (int*)(ws + 7600128);      //        512
    u16* x16     = (u16*)(ws + 7600640);      // 12,800,000
    u16* aggbuf  = (u16*)(ws + 20400640);     // 25,600,000 (layer0 uses first half)
    u16* bufB    = (u16*)(ws + 46000640);     // 25,600,000
    u16* bufC    = (u16*)(ws + 71600640);     // 25,600,000
    u16* Wt0     = (u16*)(ws + 97200640);     //     32,768
    u16* Wt1     = (u16*)(ws + 97233408);     //     65,536
    u16* Wt2     = (u16*)(ws + 97298944);     //     65,536
    // total: 97,364,480 bytes

    hipMemsetAsync(cnt, 0, N_NODES * sizeof(int), stream);
    hipMemsetAsync(cursor, 0, N_NODES * sizeof(int), stream);

    count_edges<<<(N_EDGES + 255) / 256, 256, 0, stream>>>(dst, cnt);
    scan_block_sums<<<SCAN_BLOCKS, 256, 0, stream>>>(cnt, bsum);
    scan_bsum_exclusive<<<1, 128, 0, stream>>>(bsum, offsets);
    scan_write_offsets<<<SCAN_BLOCKS, 256, 0, stream>>>(cnt, bsum, offsets);
    fill_csr<<<(N_EDGES + 255) / 256, 256, 0, stream>>>(src, dst, offsets, cursor, csr);

    // conversions
    conv_f32_bf16<<<(N_NODES * 64 / 4 + 255) / 256, 256, 0, stream>>>(x, x16, N_NODES * 64 / 4);
    conv_weights<<<(128 * 128 + 255) / 256, 256, 0, stream>>>(Wl0, Wr0, 64, 128, Wt0);
    conv_weights<<<(128 * 256 + 255) / 256, 256, 0, stream>>>(Wl1, Wr1, 128, 256, Wt1);
    conv_weights<<<(128 * 256 + 255) / 256, 256, 0, stream>>>(Wl2, Wr2, 128, 256, Wt2);

    const int aggGrid  = N_NODES / 4;               // 25000
    const int gemmGrid = (N_NODES + 63) / 64;       // 1563

    // layer 0
    aggregate_bf16<64><<<aggGrid, 256, 0, stream>>>(x16, offsets, csr, aggbuf);
    gemm_mfma<64><<<gemmGrid, 256, 0, stream>>>(aggbuf, x16, Wt0, bl0, bufB);
    // layer 1
    aggregate_bf16<128><<<aggGrid, 256, 0, stream>>>(bufB, offsets, csr, aggbuf);
    gemm_mfma<128><<<gemmGrid, 256, 0, stream>>>(aggbuf, bufB, Wt1, bl1, bufC);
    // layer 2
    aggregate_bf16<128><<<aggGrid, 256, 0, stream>>>(bufC, offsets, csr, aggbuf);
    gemm_mfma<128><<<gemmGrid, 256, 0, stream>>>(aggbuf, bufC, Wt2, bl2, bufB);

    pool_ln_decode<<<N_GRAPHS, 128, 0, stream>>>(bufB, batch, ln_g, ln_b, Wd, bd, out);
}

// Round 3
// 550.310 us; speedup vs baseline: 1.7622x; 1.5099x over previous
//
#include <hip/hip_runtime.h>

#define N_NODES  100000
#define N_EDGES  1600000
#define N_GRAPHS 512
#define LN_EPS   1e-5f

#define SCAN_CHUNK  1024
#define SCAN_BLOCKS ((N_NODES + SCAN_CHUNK - 1) / SCAN_CHUNK)  // 98

typedef unsigned short u16;
typedef unsigned int   u32;
typedef __attribute__((ext_vector_type(8))) short bf16x8;
typedef __attribute__((ext_vector_type(4))) float f32x4;

__device__ __forceinline__ float b2f(u16 v) {
    u32 u = ((u32)v) << 16;
    return __builtin_bit_cast(float, u);
}
__device__ __forceinline__ u16 f2b(float f) {
    u32 u = __builtin_bit_cast(u32, f);
    u32 r = (u + 0x7fffu + ((u >> 16) & 1u)) >> 16;  // RNE
    return (u16)r;
}

// ---------------- CSR build ----------------

__global__ void count_edges(const int* __restrict__ dst, int* __restrict__ cnt) {
    int e = blockIdx.x * blockDim.x + threadIdx.x;
    if (e < N_EDGES) atomicAdd(&cnt[dst[e]], 1);
}

__global__ void scan_block_sums(const int* __restrict__ cnt, int* __restrict__ bsum) {
    __shared__ int sh[256];
    int base = blockIdx.x * SCAN_CHUNK;
    int t = threadIdx.x;
    int s = 0;
    for (int j = t; j < SCAN_CHUNK; j += 256) {
        int i = base + j;
        s += (i < N_NODES) ? cnt[i] : 0;
    }
    sh[t] = s; __syncthreads();
    for (int off = 128; off > 0; off >>= 1) {
        if (t < off) sh[t] += sh[t + off];
        __syncthreads();
    }
    if (t == 0) bsum[blockIdx.x] = sh[0];
}

__global__ void scan_bsum_exclusive(int* __restrict__ bsum, int* __restrict__ offsets) {
    __shared__ int sh[128];
    int t = threadIdx.x;
    int v = (t < SCAN_BLOCKS) ? bsum[t] : 0;
    sh[t] = v; __syncthreads();
    for (int off = 1; off < 128; off <<= 1) {
        int add = (t >= off) ? sh[t - off] : 0;
        __syncthreads();
        sh[t] += add;
        __syncthreads();
    }
    if (t < SCAN_BLOCKS) bsum[t] = sh[t] - v;   // exclusive
    if (t == 127) offsets[N_NODES] = sh[127];
}

__global__ void scan_write_offsets(const int* __restrict__ cnt, const int* __restrict__ bsum,
                                   int* __restrict__ offsets) {
    __shared__ int sh[256];
    int b = blockIdx.x, t = threadIdx.x;
    int base = b * SCAN_CHUNK + t * 4;
    int c[4];
    #pragma unroll
    for (int j = 0; j < 4; j++) {
        int i = base + j;
        c[j] = (i < N_NODES) ? cnt[i] : 0;
    }
    int tsum = c[0] + c[1] + c[2] + c[3];
    sh[t] = tsum; __syncthreads();
    for (int off = 1; off < 256; off <<= 1) {
        int add = (t >= off) ? sh[t - off] : 0;
        __syncthreads();
        sh[t] += add;
        __syncthreads();
    }
    int run = sh[t] - tsum + bsum[b];
    #pragma unroll
    for (int j = 0; j < 4; j++) {
        int i = base + j;
        if (i < N_NODES) offsets[i] = run;
        run += c[j];
    }
}

__global__ void fill_csr(const int* __restrict__ src, const int* __restrict__ dst,
                         const int* __restrict__ offsets, int* __restrict__ cursor,
                         int* __restrict__ csr) {
    int e = blockIdx.x * blockDim.x + threadIdx.x;
    if (e < N_EDGES) {
        int d = dst[e];
        int pos = offsets[d] + atomicAdd(&cursor[d], 1);
        csr[pos] = src[e];
    }
}

// ---------------- dtype conversions ----------------

__global__ __launch_bounds__(256)
void conv_f32_bf16(const float* __restrict__ in, u16* __restrict__ out, int n4) {
    int i = blockIdx.x * 256 + threadIdx.x;
    if (i < n4) {
        float4 v = ((const float4*)in)[i];
        u32 lo = (u32)f2b(v.x) | ((u32)f2b(v.y) << 16);
        u32 hi = (u32)f2b(v.z) | ((u32)f2b(v.w) << 16);
        ((uint2*)out)[i] = make_uint2(lo, hi);
    }
}

// Wt[c][k] = bf16( k<K1 ? Wl[k][c] : Wr[k-K1][c] ), c in [0,128), k in [0,KC)
__global__ __launch_bounds__(256)
void conv_weights(const float* __restrict__ Wl, const float* __restrict__ Wr,
                  int K1, int KC, u16* __restrict__ Wt) {
    int idx = blockIdx.x * 256 + threadIdx.x;
    if (idx >= 128 * KC) return;
    int c = idx / KC, k = idx % KC;
    float v = (k < K1) ? Wl[k * 128 + c] : Wr[(k - K1) * 128 + c];
    Wt[idx] = f2b(v);
}

// ---------------- mean aggregation (bf16 gather via CSR) ----------------
// 32 lanes per node (full row covered by 32 lanes), 8 nodes per 256-thr block.
// 4-way edge unroll with independent partial accumulators -> 4 gathers in
// flight per node, 8 per wave.

template<int F>
__global__ __launch_bounds__(256)
void aggregate_bf16(const u16* __restrict__ in, const int* __restrict__ offsets,
                    const int* __restrict__ csr, u16* __restrict__ out) {
    int grp = threadIdx.x >> 5;       // 0..7 node slot in block
    int sub = threadIdx.x & 31;
    int n = blockIdx.x * 8 + grp;     // grid 12500 * 8 == N_NODES exactly
    int o0 = offsets[n], o1 = offsets[n + 1];
    int d = o1 - o0;
    float inv = 1.0f / (float)(d > 1 ? d : 1);

    if (F == 128) {
        const uint2* base = (const uint2*)in;      // row stride 32 uint2
        float acc[4][4];
        #pragma unroll
        for (int j = 0; j < 4; j++)
            #pragma unroll
            for (int c = 0; c < 4; c++) acc[j][c] = 0.f;

        int o = o0;
        for (; o + 4 <= o1; o += 4) {
            int s0 = csr[o + 0], s1 = csr[o + 1], s2 = csr[o + 2], s3 = csr[o + 3];
            uint2 v0 = base[(size_t)s0 * 32 + sub];
            uint2 v1 = base[(size_t)s1 * 32 + sub];
            uint2 v2 = base[(size_t)s2 * 32 + sub];
            uint2 v3 = base[(size_t)s3 * 32 + sub];
            acc[0][0] += b2f((u16)(v0.x & 0xffffu)); acc[0][1] += b2f((u16)(v0.x >> 16));
            acc[0][2] += b2f((u16)(v0.y & 0xffffu)); acc[0][3] += b2f((u16)(v0.y >> 16));
            acc[1][0] += b2f((u16)(v1.x & 0xffffu)); acc[1][1] += b2f((u16)(v1.x >> 16));
            acc[1][2] += b2f((u16)(v1.y & 0xffffu)); acc[1][3] += b2f((u16)(v1.y >> 16));
            acc[2][0] += b2f((u16)(v2.x & 0xffffu)); acc[2][1] += b2f((u16)(v2.x >> 16));
            acc[2][2] += b2f((u16)(v2.y & 0xffffu)); acc[2][3] += b2f((u16)(v2.y >> 16));
            acc[3][0] += b2f((u16)(v3.x & 0xffffu)); acc[3][1] += b2f((u16)(v3.x >> 16));
            acc[3][2] += b2f((u16)(v3.y & 0xffffu)); acc[3][3] += b2f((u16)(v3.y >> 16));
        }
        for (; o < o1; o++) {
            int s = csr[o];
            uint2 v = base[(size_t)s * 32 + sub];
            acc[0][0] += b2f((u16)(v.x & 0xffffu)); acc[0][1] += b2f((u16)(v.x >> 16));
            acc[0][2] += b2f((u16)(v.y & 0xffffu)); acc[0][3] += b2f((u16)(v.y >> 16));
        }
        float r0 = ((acc[0][0] + acc[1][0]) + (acc[2][0] + acc[3][0])) * inv;
        float r1 = ((acc[0][1] + acc[1][1]) + (acc[2][1] + acc[3][1])) * inv;
        float r2 = ((acc[0][2] + acc[1][2]) + (acc[2][2] + acc[3][2])) * inv;
        float r3 = ((acc[0][3] + acc[1][3]) + (acc[2][3] + acc[3][3])) * inv;
        uint2 w;
        w.x = (u32)f2b(r0) | ((u32)f2b(r1) << 16);
        w.y = (u32)f2b(r2) | ((u32)f2b(r3) << 16);
        ((uint2*)out)[(size_t)n * 32 + sub] = w;
    } else {
        const u32* base = (const u32*)in;          // row stride 32 u32
        float acc[4][2];
        #pragma unroll
        for (int j = 0; j < 4; j++) { acc[j][0] = 0.f; acc[j][1] = 0.f; }

        int o = o0;
        for (; o + 4 <= o1; o += 4) {
            int s0 = csr[o + 0], s1 = csr[o + 1], s2 = csr[o + 2], s3 = csr[o + 3];
            u32 v0 = base[(size_t)s0 * 32 + sub];
            u32 v1 = base[(size_t)s1 * 32 + sub];
            u32 v2 = base[(size_t)s2 * 32 + sub];
            u32 v3 = base[(size_t)s3 * 32 + sub];
            acc[0][0] += b2f((u16)(v0 & 0xffffu)); acc[0][1] += b2f((u16)(v0 >> 16));
            acc[1][0] += b2f((u16)(v1 & 0xffffu)); acc[1][1] += b2f((u16)(v1 >> 16));
            acc[2][0] += b2f((u16)(v2 & 0xffffu)); acc[2][1] += b2f((u16)(v2 >> 16));
            acc[3][0] += b2f((u16)(v3 & 0xffffu)); acc[3][1] += b2f((u16)(v3 >> 16));
        }
        for (; o < o1; o++) {
            int s = csr[o];
            u32 v = base[(size_t)s * 32 + sub];
            acc[0][0] += b2f((u16)(v & 0xffffu)); acc[0][1] += b2f((u16)(v >> 16));
        }
        float r0 = ((acc[0][0] + acc[1][0]) + (acc[2][0] + acc[3][0])) * inv;
        float r1 = ((acc[0][1] + acc[1][1]) + (acc[2][1] + acc[3][1])) * inv;
        ((u32*)out)[(size_t)n * 32 + sub] = (u32)f2b(r0) | ((u32)f2b(r1) << 16);
    }
}

// ---------------- fused dual GEMM via MFMA ----------------
// out[M][128] = relu( A1[M][KHALF] @ W1 + A2[M][KHALF] @ W2 + bias ), bf16 in/out, fp32 acc.
// Wt[128][2*KHALF]: concatenated transposed weights (Wt[c][k]).
// Block: 256 threads = 4 waves, 64 rows. Wave w owns cols [w*32, w*32+32).
// B fragments live in registers for the whole kernel (no LDS at all).

template<int KHALF>
__global__ __launch_bounds__(256)
void gemm_mfma(const u16* __restrict__ A1, const u16* __restrict__ A2,
               const u16* __restrict__ Wt, const float* __restrict__ bias,
               u16* __restrict__ out) {
    constexpr int KC  = 2 * KHALF;
    constexpr int NKS = KC / 32;

    int t = threadIdx.x;
    int lane = t & 63, w = t >> 6;
    int l15 = lane & 15, l4 = lane >> 4;
    int mbase = blockIdx.x * 64;

    bf16x8 bfr[2][NKS];
    #pragma unroll
    for (int ct = 0; ct < 2; ct++)
        #pragma unroll
        for (int ks = 0; ks < NKS; ks++) {
            int row = w * 32 + ct * 16 + l15;          // output col
            int kb  = ks * 32 + l4 * 8;
            bfr[ct][ks] = *reinterpret_cast<const bf16x8*>(Wt + row * KC + kb);
        }

    f32x4 acc[4][2];
    #pragma unroll
    for (int i = 0; i < 4; i++)
        #pragma unroll
        for (int j = 0; j < 2; j++)
            acc[i][j] = (f32x4){0.f, 0.f, 0.f, 0.f};

    const bf16x8 zfr = {0, 0, 0, 0, 0, 0, 0, 0};

    #pragma unroll
    for (int ks = 0; ks < NKS; ks++) {
        const u16* Ab = (ks < NKS / 2) ? A1 : A2;
        int kb = (ks < NKS / 2) ? (ks * 32 + l4 * 8) : ((ks - NKS / 2) * 32 + l4 * 8);
        bf16x8 afr[4];
        #pragma unroll
        for (int rt = 0; rt < 4; rt++) {
            int row = mbase + rt * 16 + l15;
            afr[rt] = (row < N_NODES)
                ? *reinterpret_cast<const bf16x8*>(Ab + (size_t)row * KHALF + kb)
                : zfr;
        }
        #pragma unroll
        for (int rt = 0; rt < 4; rt++)
            #pragma unroll
            for (int ct = 0; ct < 2; ct++)
                acc[rt][ct] = __builtin_amdgcn_mfma_f32_16x16x32_bf16(
                    afr[rt], bfr[ct][ks], acc[rt][ct], 0, 0, 0);
    }

    // epilogue: bias + relu, store bf16. C/D: col=lane&15, row=(lane>>4)*4+reg
    #pragma unroll
    for (int ct = 0; ct < 2; ct++) {
        int col = w * 32 + ct * 16 + l15;
        float bv = bias[col];
        #pragma unroll
        for (int rt = 0; rt < 4; rt++) {
            #pragma unroll
            for (int j = 0; j < 4; j++) {
                int row = mbase + rt * 16 + l4 * 4 + j;
                if (row < N_NODES) {
                    float v = fmaxf(acc[rt][ct][j] + bv, 0.f);
                    out[(size_t)row * 128 + col] = f2b(v);
                }
            }
        }
    }
}

// ---------------- pool + LayerNorm + decode ----------------

__global__ __launch_bounds__(128)
void pool_ln_decode(const u16* __restrict__ h, const int* __restrict__ batch,
                    const float* __restrict__ ln_g, const float* __restrict__ ln_b,
                    const float* __restrict__ Wd, const float* __restrict__ bd,
                    float* __restrict__ out) {
    __shared__ float red[128];
    __shared__ int bounds[2];
    int g = blockIdx.x, c = threadIdx.x;
    if (c < 2) {
        int target = g + c;
        int lo = 0, hi = N_NODES;
        while (lo < hi) {
            int mid = (lo + hi) >> 1;
            if (batch[mid] < target) lo = mid + 1; else hi = mid;
        }
        bounds[c] = lo;
    }
    __syncthreads();
    int start = bounds[0], end = bounds[1];

    float s = 0.f;
    for (int r = start; r < end; r++) s += b2f(h[(size_t)r * 128 + c]);

    red[c] = s; __syncthreads();
    for (int off = 64; off > 0; off >>= 1) {
        if (c < off) red[c] += red[c + off];
        __syncthreads();
    }
    float mu = red[0] * (1.0f / 128.f);
    __syncthreads();

    float d = s - mu;
    red[c] = d * d; __syncthreads();
    for (int off = 64; off > 0; off >>= 1) {
        if (c < off) red[c] += red[c + off];
        __syncthreads();
    }
    float var = red[0] * (1.0f / 128.f);
    __syncthreads();

    float gn = d * rsqrtf(var + LN_EPS) * ln_g[c] + ln_b[c];

    red[c] = gn * Wd[c * 2 + 0]; __syncthreads();
    for (int off = 64; off > 0; off >>= 1) {
        if (c < off) red[c] += red[c + off];
        __syncthreads();
    }
    float o0 = red[0];
    __syncthreads();

    red[c] = gn * Wd[c * 2 + 1]; __syncthreads();
    for (int off = 64; off > 0; off >>= 1) {
        if (c < off) red[c] += red[c + off];
        __syncthreads();
    }
    if (c == 0) {
        out[g * 2 + 0] = o0 + bd[0];
        out[g * 2 + 1] = red[0] + bd[1];
    }
}

// ---------------- host launcher ----------------

extern "C" void kernel_launch(void* const* d_in, const int* in_sizes, int n_in,
                              void* d_out, int out_size, void* d_ws, size_t ws_size,
                              hipStream_t stream) {
    (void)in_sizes; (void)n_in; (void)out_size; (void)ws_size;

    const float* x     = (const float*)d_in[0];
    const int*   ei    = (const int*)d_in[1];
    const int*   batch = (const int*)d_in[2];
    const float* Wl0 = (const float*)d_in[3];
    const float* bl0 = (const float*)d_in[4];
    const float* Wr0 = (const float*)d_in[5];
    const float* Wl1 = (const float*)d_in[6];
    const float* bl1 = (const float*)d_in[7];
    const float* Wr1 = (const float*)d_in[8];
    const float* Wl2 = (const float*)d_in[9];
    const float* bl2 = (const float*)d_in[10];
    const float* Wr2 = (const float*)d_in[11];
    const float* ln_g = (const float*)d_in[12];
    const float* ln_b = (const float*)d_in[13];
    const float* Wd  = (const float*)d_in[14];
    const float* bd  = (const float*)d_in[15];
    float* out = (float*)d_out;

    const int* src = ei;
    const int* dst = ei + N_EDGES;

    // workspace layout (bytes)
    char* ws = (char*)d_ws;
    int* csr     = (int*)(ws + 0);            //  6,400,000
    int* offsets = (int*)(ws + 6400000);      //    400,004
    int* cnt     = (int*)(ws + 6800128);      //    400,000
    int* cursor  = (int*)(ws + 7200128);      //    400,000
    int* bsum    = (int*)(ws + 7600128);      //        512
    u16* x16     = (u16*)(ws + 7600640);      // 12,800,000
    u16* aggbuf  = (u16*)(ws + 20400640);     // 25,600,000 (layer0 uses first half)
    u16* bufB    = (u16*)(ws + 46000640);     // 25,600,000
    u16* bufC    = (u16*)(ws + 71600640);     // 25,600,000
    u16* Wt0     = (u16*)(ws + 97200640);     //     32,768
    u16* Wt1     = (u16*)(ws + 97233408);     //     65,536
    u16* Wt2     = (u16*)(ws + 97298944);     //     65,536
    // total: 97,364,480 bytes

    hipMemsetAsync(cnt, 0, N_NODES * sizeof(int), stream);
    hipMemsetAsync(cursor, 0, N_NODES * sizeof(int), stream);

    count_edges<<<(N_EDGES + 255) / 256, 256, 0, stream>>>(dst, cnt);
    scan_block_sums<<<SCAN_BLOCKS, 256, 0, stream>>>(cnt, bsum);
    scan_bsum_exclusive<<<1, 128, 0, stream>>>(bsum, offsets);
    scan_write_offsets<<<SCAN_BLOCKS, 256, 0, stream>>>(cnt, bsum, offsets);
    fill_csr<<<(N_EDGES + 255) / 256, 256, 0, stream>>>(src, dst, offsets, cursor, csr);

    // conversions
    conv_f32_bf16<<<(N_NODES * 64 / 4 + 255) / 256, 256, 0, stream>>>(x, x16, N_NODES * 64 / 4);
    conv_weights<<<(128 * 128 + 255) / 256, 256, 0, stream>>>(Wl0, Wr0, 64, 128, Wt0);
    conv_weights<<<(128 * 256 + 255) / 256, 256, 0, stream>>>(Wl1, Wr1, 128, 256, Wt1);
    conv_weights<<<(128 * 256 + 255) / 256, 256, 0, stream>>>(Wl2, Wr2, 128, 256, Wt2);

    const int aggGrid  = N_NODES / 8;               // 12500 (exact)
    const int gemmGrid = (N_NODES + 63) / 64;       // 1563

    // layer 0
    aggregate_bf16<64><<<aggGrid, 256, 0, stream>>>(x16, offsets, csr, aggbuf);
    gemm_mfma<64><<<gemmGrid, 256, 0, stream>>>(aggbuf, x16, Wt0, bl0, bufB);
    // layer 1
    aggregate_bf16<128><<<aggGrid, 256, 0, stream>>>(bufB, offsets, csr, aggbuf);
    gemm_mfma<128><<<gemmGrid, 256, 0, stream>>>(aggbuf, bufB, Wt1, bl1, bufC);
    // layer 2
    aggregate_bf16<128><<<aggGrid, 256, 0, stream>>>(bufC, offsets, csr, aggbuf);
    gemm_mfma<128><<<gemmGrid, 256, 0, stream>>>(aggbuf, bufC, Wt2, bl2, bufB);

    pool_ln_decode<<<N_GRAPHS, 128, 0, stream>>>(bufB, batch, ln_g, ln_b, Wd, bd, out);
}